// Round 6
// baseline (366.826 us; speedup 1.0000x reference)
//
#include <hip/hip_runtime.h>
#include <cstdint>

#define NROWS_HALF 32768
#define NPTS 1000
#define QC_OFF 4194304            // quantized_coord offset in d_out (floats)
#define LOSS_OFF 8388608          // loss offset in d_out (floats)

// ws layout in ushort units (bf16 stored as raw ushort):
//   U_VH  [1040][64]: rows 0..999 coord vecs * log2e (RN hi), 1000..1007 zero,
//                     rows 1008..1039 = M codes * log2e (m = row-1008)
//   U_VL  [1040][64]: matching RN lo residuals
//   U_VHT [64][1024]: d-major coord vecs UNSCALED (RN hi; cols 1000..1023 zero)
//   byte 397312: fp32 loss accumulator
#define U_VH 0
#define U_VL 66560
#define U_VHT 133120
#define WS_LOSS_BYTE 397312

#define X_STRIDE 68
#define WSTRIDE 1028              // ushort stride for W_s rows (2-way-max banks)

#define LOG2E 1.4426950408889634f
#define LN2   0.6931471805599453f

typedef short short8 __attribute__((ext_vector_type(8)));
typedef float float4v __attribute__((ext_vector_type(4)));

#define MFMA16(a, b, c) __builtin_amdgcn_mfma_f32_16x16x32_bf16((a), (b), (c), 0, 0, 0)

__device__ uint32_t g_ticket;     // block-completion ticket (zeroed by setup each launch)

// ---------------- Threefry-2x32 (20 rounds), matches JAX ----------------
__host__ __device__ __forceinline__ void tf2x32(uint32_t k0, uint32_t k1,
                                                uint32_t x0, uint32_t x1,
                                                uint32_t& o0, uint32_t& o1) {
  const uint32_t k2 = k0 ^ k1 ^ 0x1BD11BDAu;
#define TF_R(r) { x0 += x1; x1 = (x1 << (r)) | (x1 >> (32 - (r))); x1 ^= x0; }
  x0 += k0; x1 += k1;
  TF_R(13) TF_R(15) TF_R(26) TF_R(6)
  x0 += k1; x1 += k2 + 1u;
  TF_R(17) TF_R(29) TF_R(16) TF_R(24)
  x0 += k2; x1 += k0 + 2u;
  TF_R(13) TF_R(15) TF_R(26) TF_R(6)
  x0 += k0; x1 += k1 + 3u;
  TF_R(17) TF_R(29) TF_R(16) TF_R(24)
  x0 += k1; x1 += k2 + 4u;
  TF_R(13) TF_R(15) TF_R(26) TF_R(6)
  x0 += k2; x1 += k0 + 5u;
#undef TF_R
  o0 = x0; o1 = x1;
}

// neglog_u(bits) = -log(u + 1e-20), u = (bits>>9 | 1.0f) - 1.0f.
// exp(gumbel/2) == rsqrt(neglog_u + 1e-20) exactly (gumbel = -log(-log(u+e)+e)).
__device__ __forceinline__ float neglog_u(uint32_t bits) {
  const uint32_t mant = bits >> 9;
  const float u = __uint_as_float(mant | 0x3f800000u) - 1.0f;
  const float delta = (float)(8388608u - mant) * 1.1920928955078125e-7f;
  float nl;
  if (delta < 0.00390625f) {
    nl = delta + 0.5f * delta * delta + 0.33333333f * delta * delta * delta;
  } else {
    nl = -LN2 * __builtin_amdgcn_logf(u + 1e-20f);
  }
  return nl;
}

// round-to-nearest-even bf16 (returns 16-bit pattern in low bits)
__device__ __forceinline__ uint32_t rn16(float f) {
  uint32_t u = __float_as_uint(f);
  return (u + 0x7FFFu + ((u >> 16) & 1u)) >> 16;
}

__device__ __forceinline__ void split2_rn(float f0, float f1, uint32_t& hi, uint32_t& lo) {
  uint32_t h0 = rn16(f0), h1 = rn16(f1);
  hi = h0 | (h1 << 16);
  float l0 = f0 - __uint_as_float(h0 << 16);
  float l1 = f1 - __uint_as_float(h1 << 16);
  lo = rn16(l0) | (rn16(l1) << 16);
}

__device__ __forceinline__ void split8_rn(const float* p, short8& hi, short8& lo) {
  float4 f0 = *(const float4*)p;
  float4 f1 = *(const float4*)(p + 4);
  union { uint32_t u[4]; short8 s; } H, L;
  split2_rn(f0.x, f0.y, H.u[0], L.u[0]);
  split2_rn(f0.z, f0.w, H.u[1], L.u[1]);
  split2_rn(f1.x, f1.y, H.u[2], L.u[2]);
  split2_rn(f1.z, f1.w, H.u[3], L.u[3]);
  hi = H.s; lo = L.s;
}

__device__ __forceinline__ short8 as_s8(uint4 v) {
  union { uint4 u; short8 s; } c; c.u = v; return c.s;
}

__device__ __forceinline__ float grid_vec(int n, int c, const float* __restrict__ lw,
                                          const float* __restrict__ lb) {
  int jx = (n / 10) % 10, iy = n / 100, kz = n % 10;
  const double step = 1.5 / 9.0;
  float gx = (float)(jx * step), gy = (float)(iy * step), gz = (float)(kz * step);
  return gx * lw[c * 3 + 0] + gy * lw[c * 3 + 1] + gz * lw[c * 3 + 2] + lb[c];
}

// one 16-col tile of GEMM1: 3-MFMA split-bf16 (hi+lo), B rows nb..nb+15
// split-load form: 2 loads -> 3 MFMAs -> 2 loads -> 3 MFMAs (lower live pressure)
__device__ __forceinline__ float4v tile_mfma(const ushort* __restrict__ Vh,
                                             const ushort* __restrict__ Vl,
                                             int nb, const short8* ah, const short8* al) {
  uint4 bh0 = *(const uint4*)(Vh + nb);
  uint4 bl0 = *(const uint4*)(Vl + nb);
  float4v acc = {0.f, 0.f, 0.f, 0.f};
  acc = MFMA16(ah[0], as_s8(bh0), acc);
  acc = MFMA16(ah[0], as_s8(bl0), acc);
  acc = MFMA16(al[0], as_s8(bh0), acc);
  uint4 bh1 = *(const uint4*)(Vh + nb + 32);
  uint4 bl1 = *(const uint4*)(Vl + nb + 32);
  acc = MFMA16(ah[1], as_s8(bh1), acc);
  acc = MFMA16(ah[1], as_s8(bl1), acc);
  acc = MFMA16(al[1], as_s8(bh1), acc);
  return acc;
}

// ---------------- setup: V tables + M codes + loss/ticket=0 ----------------
__global__ void setup_kernel(const float* __restrict__ lw, const float* __restrict__ lb,
                             const float* __restrict__ emb, const float* __restrict__ lws,
                             ushort* __restrict__ wsu) {
  int idx = blockIdx.x * 256 + threadIdx.x;
  if (idx < 66560) {
    int n = idx >> 6, c = idx & 63;
    float v;
    if (n < NPTS) {
      v = grid_vec(n, c, lw, lb);
    } else if (n < 1008) {
      v = 0.f;
    } else {
      int m = n - 1008, k = m >> 3;
      float a = 0.f;
      #pragma unroll
      for (int e = 0; e < 16; ++e) a += emb[m * 16 + e] * lws[(k * 16 + e) * 64 + c];
      v = a;
    }
    v *= LOG2E;                        // GEMM1 logits in log2 domain
    uint32_t h = rn16(v);
    float fl = v - __uint_as_float(h << 16);
    wsu[U_VH + idx] = (ushort)h;
    wsu[U_VL + idx] = (ushort)rn16(fl);
  } else if (idx < 132096) {
    int i2 = idx - 66560;              // d*1024 + n
    int d = i2 >> 10, n = i2 & 1023;
    float v = (n < NPTS) ? grid_vec(n, d, lw, lb) : 0.f;   // UNSCALED for GEMM2
    wsu[U_VHT + i2] = (ushort)rn16(v);
  } else if (idx == 132096) {
    *(float*)((char*)wsu + WS_LOSS_BYTE) = 0.f;
    g_ticket = 0u;
  }
}

// ---------------- fused main kernel: 4096 blocks x 256 ----------------
// r0 loop structure (unroll 2, fresh weight-exp => short live ranges, fits 64 VGPR)
// + r3 math (log2-domain tables, rsqrt-gumbel, rcp/ticket finalize).
__global__ __launch_bounds__(256, 4) void fused_kernel(
    const float* __restrict__ inp, const float* __restrict__ emb,
    const float* __restrict__ lw, const float* __restrict__ lb,
    const ushort* __restrict__ wsu, float* __restrict__ out,
    float* __restrict__ loss_acc,
    uint32_t kc0, uint32_t kc1, uint32_t kp0, uint32_t kp1) {

  __shared__ float x_s[16 * X_STRIDE];    // input rows; later q output
  __shared__ ushort W_s[16 * WSTRIDE];    // bf16 gumbel weights
  __shared__ float xp_s[16 * 32];         // codebook logits (log2 domain)
  __shared__ float red_s[192];            // [0,64) s0, [64,128) s1, [128,192) sw
  __shared__ float max_s[16];             // exact per-row logit max (log2 domain)
  __shared__ float kl_s;

  const int t = threadIdx.x;
  const int lane = t & 63;
  const int w = t >> 6;
  const int q = lane >> 4;
  const int mn = lane & 15;
  const int g0 = blockIdx.x * 8;

  if (t == 0) kl_s = 0.f;

  // per-lane projection coefficients (lane = channel c)
  const float pw0 = lw[lane * 3 + 0];
  const float pw1 = lw[lane * 3 + 1];
  const float pw2 = lw[lane * 3 + 2];
  const float pbb = lb[lane];

  // ---- load 16 input rows + EXACT per-row logit max (log2 domain) ----
  // max over grid = 1.5*(relu(u0)+relu(u1)+relu(u2)) + beta, u = W^T x, beta = x.b
  #pragma unroll
  for (int it = 0; it < 4; ++it) {
    int rl = it * 4 + w;
    int row = (rl < 8) ? (g0 + rl) : (g0 + rl - 8 + NROWS_HALF);
    float v = inp[row * 64 + lane];
    x_s[rl * X_STRIDE + lane] = v;
    float u0 = v * pw0, u1 = v * pw1, u2 = v * pw2, u3 = v * pbb;
    #pragma unroll
    for (int off = 32; off > 0; off >>= 1) {
      u0 += __shfl_xor(u0, off);
      u1 += __shfl_xor(u1, off);
      u2 += __shfl_xor(u2, off);
      u3 += __shfl_xor(u3, off);
    }
    if (lane == 0)
      max_s[rl] = LOG2E *
          (1.5f * (fmaxf(u0, 0.f) + fmaxf(u1, 0.f) + fmaxf(u2, 0.f)) + u3);
  }
  __syncthreads();

  // ---- A fragments (rows = local rows, m = mn) ----
  short8 ah[2], al[2];
  #pragma unroll
  for (int s = 0; s < 2; ++s)
    split8_rn(&x_s[mn * X_STRIDE + s * 32 + q * 8], ah[s], al[s]);

  float mrow[4], mh[4];
  #pragma unroll
  for (int r = 0; r < 4; ++r) { mrow[r] = max_s[q * 4 + r]; mh[r] = 0.5f * mrow[r]; }

  const ushort* Vh = wsu + U_VH;
  const ushort* Vl = wsu + U_VL;
  const int rbase = (q & 1) * 4;
  const bool low = (q < 2);

  float s0[4] = {0.f, 0.f, 0.f, 0.f};
  float s1[4] = {0.f, 0.f, 0.f, 0.f};
  float sw[4] = {0.f, 0.f, 0.f, 0.f};

  // ---- streaming GEMM1 + KL stats + gumbel weights, tile-pairs (jA, jA+32) ----
  // weight = exp2(x'/2 - m'/2) * rsqrt(neglog_u + 1e-20)   [fresh exp2: short live]
  #pragma unroll 2
  for (int i = 0; i < 8; ++i) {
    const int jA = w + 4 * i, jB = jA + 32;
    float4v accA = tile_mfma(Vh, Vl, (jA * 16 + mn) * 64 + q * 8, ah, al);
    float4v accB;
    if (jB < 63) {
      accB = tile_mfma(Vh, Vl, (jB * 16 + mn) * 64 + q * 8, ah, al);
      if (jB == 62 && mn >= 8) accB = (float4v){-1e30f, -1e30f, -1e30f, -1e30f};
    } else {
      accB = (float4v){-1e30f, -1e30f, -1e30f, -1e30f};
    }
    const int colA = jA * 16 + mn, colB = jB * 16 + mn;
    #pragma unroll
    for (int r = 0; r < 4; ++r) {
      float eA = __builtin_amdgcn_exp2f(accA[r] - mrow[r]);
      float eB = __builtin_amdgcn_exp2f(accB[r] - mrow[r]);
      s0[r] += eA; s1[r] += eA * accA[r];
      s0[r] += eB; s1[r] += eB * accB[r];
      // gumbel noise (threefry-paired via shfl_xor 32)
      const uint32_t rowAg = (uint32_t)(g0 + rbase + r);
      const uint32_t nown = low ? (uint32_t)colA : (uint32_t)colB;
      uint32_t y0, y1;
      uint32_t j0 = rowAg * 1000u + nown;
      tf2x32(kc0, kc1, j0, j0 + 32768000u, y0, y1);
      uint32_t send = low ? y1 : y0;
      uint32_t recv = (uint32_t)__shfl_xor((int)send, 32);
      uint32_t bA = low ? y0 : recv;
      uint32_t bB = low ? recv : y1;
      const int myrow = q * 4 + r;
      float wA = __builtin_amdgcn_exp2f(accA[r] * 0.5f - mh[r]) *
                 __builtin_amdgcn_rsqf(neglog_u(bA) + 1e-20f);
      uint32_t hA = rn16(wA);
      sw[r] += __uint_as_float(hA << 16);
      W_s[myrow * WSTRIDE + (colA ^ (r * 8))] = (ushort)hA;
      float wB = __builtin_amdgcn_exp2f(accB[r] * 0.5f - mh[r]) *
                 __builtin_amdgcn_rsqf(neglog_u(bB) + 1e-20f);
      uint32_t hB = rn16(wB);
      sw[r] += __uint_as_float(hB << 16);
      if (colB < 1008) W_s[myrow * WSTRIDE + (colB ^ (r * 8))] = (ushort)hB;
    }
  }

  // ---- reduce stats over mn within quad; stash wave-partials ----
  #pragma unroll
  for (int off = 1; off < 16; off <<= 1) {
    #pragma unroll
    for (int r = 0; r < 4; ++r) {
      s0[r] += __shfl_xor(s0[r], off);
      s1[r] += __shfl_xor(s1[r], off);
      sw[r] += __shfl_xor(sw[r], off);
    }
  }
  if (mn == 0) {
    #pragma unroll
    for (int r = 0; r < 4; ++r) {
      red_s[w * 16 + q * 4 + r] = s0[r];
      red_s[64 + w * 16 + q * 4 + r] = s1[r];
      red_s[128 + w * 16 + q * 4 + r] = sw[r];
    }
  }

  // ---- code tiles: xp logits via same A-frags (M rows 1008..1039) ----
  if (w == 0 || w == 3) {
    const int ct = (w == 0) ? 64 : 63;
    float4v acc = tile_mfma(Vh, Vl, (ct * 16 + mn) * 64 + q * 8, ah, al);
    #pragma unroll
    for (int r = 0; r < 4; ++r)
      xp_s[(q * 4 + r) * 32 + (ct - 63) * 16 + mn] = acc[r];
  }

  // ---- zero LOGICAL pad cols 1008..1023 through the per-row XOR map ----
  {
    int rowp = t >> 4;
    int cp = 1008 + (t & 15);
    W_s[rowp * WSTRIDE + (cp ^ ((rowp & 3) * 8))] = 0;
  }
  __syncthreads();

  // ---- KL finalize (t<16): natural-log terms recovered via *ln2 ----
  if (t < 16) {
    float S0 = (red_s[t] + red_s[16 + t]) + (red_s[32 + t] + red_s[48 + t]);
    float S1 = (red_s[64 + t] + red_s[80 + t]) + (red_s[96 + t] + red_s[112 + t]);
    atomicAdd(&kl_s, LN2 * ((S1 * __builtin_amdgcn_rcpf(S0) - max_s[t]) -
                            __builtin_amdgcn_logf(S0)) + 6.9077552789821f);
  }

  // ---- GEMM2 (MFMA): qc[16][64] = W[16][1024] . V; wave w -> d-tile w ----
  {
    const ushort* VhT = wsu + U_VHT;
    const int dq = w * 16 + mn;
    const int swz = (mn & 3) * 8;
    float4v acc = {0.f, 0.f, 0.f, 0.f};
    for (int s = 0; s < 32; ++s) {
      uint4 aw = *(const uint4*)(W_s + mn * WSTRIDE + ((s * 32 + q * 8) ^ swz));
      uint4 bh = *(const uint4*)(VhT + dq * 1024 + s * 32 + q * 8);
      acc = MFMA16(as_s8(aw), as_s8(bh), acc);
    }
    #pragma unroll
    for (int r = 0; r < 4; ++r) {
      int m = q * 4 + r;
      float sww = (red_s[128 + m] + red_s[144 + m]) + (red_s[160 + m] + red_s[176 + m]);
      int grow = (m < 8) ? (g0 + m) : (g0 + m - 8 + NROWS_HALF);
      out[QC_OFF + grow * 64 + dq] = acc[r] * __builtin_amdgcn_rcpf(sww);
    }
  }

  // ---- 5b: per (pair p, k) codebook path; 8 lanes per wave (32 units) ----
  float* q_s = x_s;   // x dead (A-frags extracted pre-loop)
  if (lane < 8) {
    const int u_ = w * 8 + lane;
    const int p = u_ >> 2, k = u_ & 3;
    const int rA = p, rB = p + 8;
    float xpA[8], xpB[8];
    #pragma unroll
    for (int n = 0; n < 8; ++n) {
      xpA[n] = xp_s[rA * 32 + k * 8 + n];
      xpB[n] = xp_s[rB * 32 + k * 8 + n];
    }
    float mA = xpA[0], mB = xpB[0];
    #pragma unroll
    for (int n = 1; n < 8; ++n) { mA = fmaxf(mA, xpA[n]); mB = fmaxf(mB, xpB[n]); }
    const uint32_t base = (uint32_t)(g0 + p) * 32u + (uint32_t)k * 8u;
    float s0A = 0.f, s1A = 0.f, s0B = 0.f, s1B = 0.f, swA = 0.f, swB = 0.f;
    float wvA[8], wvB[8];
    #pragma unroll
    for (int n = 0; n < 8; ++n) {
      float eA = __builtin_amdgcn_exp2f(xpA[n] - mA);
      float eB = __builtin_amdgcn_exp2f(xpB[n] - mB);
      s0A += eA; s1A += eA * xpA[n];
      s0B += eB; s1B += eB * xpB[n];
      uint32_t y0, y1;
      tf2x32(kp0, kp1, base + n, base + n + 1048576u, y0, y1);
      wvA[n] = __builtin_amdgcn_exp2f((xpA[n] - mA) * 0.5f) *
               __builtin_amdgcn_rsqf(neglog_u(y0) + 1e-20f);
      wvB[n] = __builtin_amdgcn_exp2f((xpB[n] - mB) * 0.5f) *
               __builtin_amdgcn_rsqf(neglog_u(y1) + 1e-20f);
      swA += wvA[n]; swB += wvB[n];
    }
    atomicAdd(&kl_s,
        LN2 * ((s1A * __builtin_amdgcn_rcpf(s0A) - mA) - __builtin_amdgcn_logf(s0A)) +
        LN2 * ((s1B * __builtin_amdgcn_rcpf(s0B) - mB) - __builtin_amdgcn_logf(s0B)) +
        4.1588830833596715f);
    float invA = __builtin_amdgcn_rcpf(swA), invB = __builtin_amdgcn_rcpf(swB);
    #pragma unroll
    for (int e = 0; e < 16; ++e) {
      float aA = 0.f, aB = 0.f;
      #pragma unroll
      for (int n = 0; n < 8; ++n) {
        float ev = emb[(k * 8 + n) * 16 + e];
        aA += wvA[n] * ev; aB += wvB[n] * ev;
      }
      q_s[rA * X_STRIDE + k * 16 + e] = aA * invA;
      q_s[rB * X_STRIDE + k * 16 + e] = aB * invB;
    }
  }
  __syncthreads();

  // ---- copyout quantized (coalesced) + loss; last block finalizes loss ----
  #pragma unroll
  for (int it = 0; it < 4; ++it) {
    int idx = it * 256 + t;
    int rl = idx >> 6, c = idx & 63;
    int row = (rl < 8) ? (g0 + rl) : (g0 + rl - 8 + NROWS_HALF);
    out[row * 64 + c] = q_s[rl * X_STRIDE + c];
  }
  if (t == 0) {
    atomicAdd(loss_acc, kl_s);
    __threadfence();
    uint32_t tk = atomicAdd(&g_ticket, 1u);
    if (tk == 4095u) {
      __threadfence();
      out[LOSS_OFF] = atomicAdd(loss_acc, 0.0f) * 0.2f;
    }
  }
}

extern "C" void kernel_launch(void* const* d_in, const int* in_sizes, int n_in,
                              void* d_out, int out_size, void* d_ws, size_t ws_size,
                              hipStream_t stream) {
  const float* inp  = (const float*)d_in[0];   // [32,2048,64]
  const float* lw   = (const float*)d_in[1];   // [64,3]
  const float* lb   = (const float*)d_in[2];   // [64]
  const float* emb  = (const float*)d_in[3];   // [32,16] normalized
  const float* lws  = (const float*)d_in[4];   // [4,16,64]
  float* out = (float*)d_out;
  ushort* wsu = (ushort*)d_ws;
  float* loss = (float*)((char*)d_ws + WS_LOSS_BYTE);

  // JAX PRNG keys: key(42) -> [0,42]; split = threefry over iota(4)
  uint32_t a0, b0, a1, b1;
  tf2x32(0u, 42u, 0u, 2u, a0, b0);
  tf2x32(0u, 42u, 1u, 3u, a1, b1);
  const uint32_t kc0 = a0, kc1 = a1;   // coord-noise key
  const uint32_t kp0 = b0, kp1 = b1;   // codebook-noise key

  setup_kernel<<<517, 256, 0, stream>>>(lw, lb, emb, lws, wsu);
  fused_kernel<<<4096, 256, 0, stream>>>(inp, emb, lw, lb, wsu, out, loss,
                                         kc0, kc1, kp0, kp1);
}

// Round 7
// 252.346 us; speedup vs baseline: 1.4537x; 1.4537x over previous
//
#include <hip/hip_runtime.h>
#include <cstdint>

#define NROWS_HALF 32768
#define QC_OFF 4194304            // quantized_coord offset in d_out (floats)
#define LOSS_OFF 8388608          // loss offset in d_out (floats)

// ws layout (ushort units): CODE_HI [32][64] at 0, CODE_LO [32][64] at 2048
// (code m rows = emb[m] @ lws[k], scaled by log2e, split bf16 hi/lo).
// fp32 loss accumulator at byte 8192.
#define U_CH 0
#define U_CL 2048
#define WS_LOSS_BYTE 8192

#define X_STRIDE 68
#define LOG2E 1.4426950408889634f
#define LN2   0.6931471805599453f

typedef short short8 __attribute__((ext_vector_type(8)));
typedef float float4v __attribute__((ext_vector_type(4)));

#define MFMA16(a, b, c) __builtin_amdgcn_mfma_f32_16x16x32_bf16((a), (b), (c), 0, 0, 0)

__device__ uint32_t g_ticket;     // block-completion ticket (zeroed by setup each launch)

// ---------------- Threefry-2x32 (20 rounds), matches JAX ----------------
__host__ __device__ __forceinline__ void tf2x32(uint32_t k0, uint32_t k1,
                                                uint32_t x0, uint32_t x1,
                                                uint32_t& o0, uint32_t& o1) {
  const uint32_t k2 = k0 ^ k1 ^ 0x1BD11BDAu;
#define TF_R(r) { x0 += x1; x1 = (x1 << (r)) | (x1 >> (32 - (r))); x1 ^= x0; }
  x0 += k0; x1 += k1;
  TF_R(13) TF_R(15) TF_R(26) TF_R(6)
  x0 += k1; x1 += k2 + 1u;
  TF_R(17) TF_R(29) TF_R(16) TF_R(24)
  x0 += k2; x1 += k0 + 2u;
  TF_R(13) TF_R(15) TF_R(26) TF_R(6)
  x0 += k0; x1 += k1 + 3u;
  TF_R(17) TF_R(29) TF_R(16) TF_R(24)
  x0 += k1; x1 += k2 + 4u;
  TF_R(13) TF_R(15) TF_R(26) TF_R(6)
  x0 += k2; x1 += k0 + 5u;
#undef TF_R
  o0 = x0; o1 = x1;
}

// neglog_u(bits) = -log(u + 1e-20), u = (bits>>9 | 1.0f) - 1.0f.
// exp(gumbel/2) == rsqrt(neglog_u + 1e-20) exactly (gumbel = -log(-log(u+e)+e)).
__device__ __forceinline__ float neglog_u(uint32_t bits) {
  const uint32_t mant = bits >> 9;
  const float u = __uint_as_float(mant | 0x3f800000u) - 1.0f;
  const float delta = (float)(8388608u - mant) * 1.1920928955078125e-7f;
  float nl;
  if (delta < 0.00390625f) {
    nl = delta + 0.5f * delta * delta + 0.33333333f * delta * delta * delta;
  } else {
    nl = -LN2 * __builtin_amdgcn_logf(u + 1e-20f);
  }
  return nl;
}

// round-to-nearest-even bf16 (returns 16-bit pattern in low bits)
__device__ __forceinline__ uint32_t rn16(float f) {
  uint32_t u = __float_as_uint(f);
  return (u + 0x7FFFu + ((u >> 16) & 1u)) >> 16;
}

__device__ __forceinline__ void split2_rn(float f0, float f1, uint32_t& hi, uint32_t& lo) {
  uint32_t h0 = rn16(f0), h1 = rn16(f1);
  hi = h0 | (h1 << 16);
  float l0 = f0 - __uint_as_float(h0 << 16);
  float l1 = f1 - __uint_as_float(h1 << 16);
  lo = rn16(l0) | (rn16(l1) << 16);
}

__device__ __forceinline__ void split8_rn(const float* p, short8& hi, short8& lo) {
  float4 f0 = *(const float4*)p;
  float4 f1 = *(const float4*)(p + 4);
  union { uint32_t u[4]; short8 s; } H, L;
  split2_rn(f0.x, f0.y, H.u[0], L.u[0]);
  split2_rn(f0.z, f0.w, H.u[1], L.u[1]);
  split2_rn(f1.x, f1.y, H.u[2], L.u[2]);
  split2_rn(f1.z, f1.w, H.u[3], L.u[3]);
  hi = H.s; lo = L.s;
}

__device__ __forceinline__ short8 as_s8(uint4 v) {
  union { uint4 u; short8 s; } c; c.u = v; return c.s;
}

// one 16-col tile of xp: 3-MFMA split-bf16 (hi+lo), B rows nb..nb+15
__device__ __forceinline__ float4v tile_mfma(const ushort* __restrict__ Vh,
                                             const ushort* __restrict__ Vl,
                                             int nb, const short8* ah, const short8* al) {
  uint4 bh0 = *(const uint4*)(Vh + nb);
  uint4 bl0 = *(const uint4*)(Vl + nb);
  float4v acc = {0.f, 0.f, 0.f, 0.f};
  acc = MFMA16(ah[0], as_s8(bh0), acc);
  acc = MFMA16(ah[0], as_s8(bl0), acc);
  acc = MFMA16(al[0], as_s8(bh0), acc);
  uint4 bh1 = *(const uint4*)(Vh + nb + 32);
  uint4 bl1 = *(const uint4*)(Vl + nb + 32);
  acc = MFMA16(ah[1], as_s8(bh1), acc);
  acc = MFMA16(ah[1], as_s8(bl1), acc);
  acc = MFMA16(al[1], as_s8(bh1), acc);
  return acc;
}

// ---------------- setup: compact code table + loss/ticket=0 ----------------
__global__ void setup_kernel(const float* __restrict__ emb, const float* __restrict__ lws,
                             ushort* __restrict__ wsu) {
  int idx = blockIdx.x * 256 + threadIdx.x;
  if (idx < 2048) {
    int m = idx >> 6, c = idx & 63, k = m >> 3;
    float a = 0.f;
    #pragma unroll
    for (int e = 0; e < 16; ++e) a += emb[m * 16 + e] * lws[(k * 16 + e) * 64 + c];
    a *= LOG2E;                      // xp logits in log2 domain
    uint32_t h = rn16(a);
    float fl = a - __uint_as_float(h << 16);
    wsu[U_CH + idx] = (ushort)h;
    wsu[U_CL + idx] = (ushort)rn16(fl);
  } else if (idx == 2048) {
    *(float*)((char*)wsu + WS_LOSS_BYTE) = 0.f;
    g_ticket = 0u;
  }
}

// ---------------- fused main kernel: 4096 blocks x 256 (4 waves) ----------------
// SEPARABLE coordinate path: logit(row,n) = u0*gx + u1*gy + u2*gz + u3 with
// gx/gy/gz each from 10 grid values => per row 30 exp2's give everything:
//   exp(logit-m) = Pa[jx]*Pb[iy]*Pc[kz]   (per-axis relu-normalized, P<=1)
//   KL closed form per row (no per-element stats)
//   weight w = sqrt(Pa)*sqrt(Pb)*sqrt(Pc)*rsqrt(neglog_u)  (no per-element exp)
//   qc via rank-4 vecs: qc_d = (step*(T1*lw0+T2*lw1+T3*lw2) + T0*lb_d)/T0,
//     T0..T3 = running sums of w, w*jx, w*iy, w*kz.
// No GEMM1, no GEMM2, no W_s. Per element: threefry + neglog + rsqrt + ~10 FMA.
__global__ __launch_bounds__(256, 4) void fused_kernel(
    const float* __restrict__ inp, const float* __restrict__ emb,
    const float* __restrict__ lw, const float* __restrict__ lb,
    const ushort* __restrict__ wsu, float* __restrict__ out,
    float* __restrict__ loss_acc,
    uint32_t kc0, uint32_t kc1, uint32_t kp0, uint32_t kp1) {

  __shared__ float x_s[16 * X_STRIDE];    // input rows; later q output
  __shared__ float xp_s[16 * 32];         // codebook logits (log2 domain)
  __shared__ float sq_s[16 * 32];         // [row][axis*10+i] = sqrt(P_axis[i])
  __shared__ float u_s[16 * 3];           // per-row u0,u1,u2
  __shared__ float swq_s[96];             // [axis][row][{S,W}]
  __shared__ float tq_s[16 * 4];          // per-row T0..T3
  __shared__ float kl_s;

  const int t = threadIdx.x;
  const int lane = t & 63;
  const int w = t >> 6;                   // 0..3
  const int q = lane >> 4;
  const int mn = lane & 15;
  const int g0 = blockIdx.x * 8;

  if (t == 0) kl_s = 0.f;

  // per-lane projection coefficients (lane = channel c)
  const float pw0 = lw[lane * 3 + 0];
  const float pw1 = lw[lane * 3 + 1];
  const float pw2 = lw[lane * 3 + 2];

  // ---- load 16 input rows + per-row u = W^T x (3 butterfly reductions) ----
  #pragma unroll
  for (int it = 0; it < 4; ++it) {
    int rl = it * 4 + w;
    int row = (rl < 8) ? (g0 + rl) : (g0 + rl - 8 + NROWS_HALF);
    float v = inp[row * 64 + lane];
    x_s[rl * X_STRIDE + lane] = v;
    float u0 = v * pw0, u1 = v * pw1, u2 = v * pw2;
    #pragma unroll
    for (int off = 32; off > 0; off >>= 1) {
      u0 += __shfl_xor(u0, off);
      u1 += __shfl_xor(u1, off);
      u2 += __shfl_xor(u2, off);
    }
    if (lane == 0) {
      u_s[rl * 3 + 0] = u0; u_s[rl * 3 + 1] = u1; u_s[rl * 3 + 2] = u2;
    }
  }
  __syncthreads();

  // ---- phase2: per (row,axis) tables: P_i = exp2((ua*g_i - 1.5*relu(ua))*log2e)
  if (t < 48) {
    const int row = t & 15, axis = t >> 4;
    const float ua = u_s[row * 3 + axis];
    const float b = 1.5f * fmaxf(ua, 0.f);
    float S = 0.f, W = 0.f;
    #pragma unroll
    for (int i = 0; i < 10; ++i) {
      float gi = (float)(i * (1.5 / 9.0));
      float lg = (ua * gi - b) * LOG2E;      // <= 0
      float P = __builtin_amdgcn_exp2f(lg);
      S += P; W += lg * P;
      sq_s[row * 32 + axis * 10 + i] = __builtin_amdgcn_sqrtf(P);
    }
    swq_s[axis * 32 + row * 2 + 0] = S;
    swq_s[axis * 32 + row * 2 + 1] = W;
  }

  // ---- A fragments for code tiles (waves 0,3 only) ----
  short8 ah[2], al[2];
  if (w == 0 || w == 3) {
    #pragma unroll
    for (int s = 0; s < 2; ++s)
      split8_rn(&x_s[mn * X_STRIDE + s * 32 + q * 8], ah[s], al[s]);
  }
  __syncthreads();

  // ---- coord KL, closed form per row (t<16) ----
  if (t < 16) {
    float Sa = swq_s[t * 2], Wa = swq_s[t * 2 + 1];
    float Sb = swq_s[32 + t * 2], Wb = swq_s[32 + t * 2 + 1];
    float Sc = swq_s[64 + t * 2], Wc = swq_s[64 + t * 2 + 1];
    float kl = LN2 * ((Wa * __builtin_amdgcn_rcpf(Sa) +
                       Wb * __builtin_amdgcn_rcpf(Sb) +
                       Wc * __builtin_amdgcn_rcpf(Sc)) -
                      __builtin_amdgcn_logf(Sa * Sb * Sc)) + 6.9077552789821f;
    atomicAdd(&kl_s, kl);
  }

  // ---- code tiles: xp logits via compact code table (M rows 0..31) ----
  if (w == 0 || w == 3) {
    const int cti = (w == 0) ? 1 : 0;
    float4v acc = tile_mfma(wsu + U_CH, wsu + U_CL, (cti * 16 + mn) * 64 + q * 8, ah, al);
    #pragma unroll
    for (int r = 0; r < 4; ++r)
      xp_s[(q * 4 + r) * 32 + cti * 16 + mn] = acc[r];
  }

  // ---- main loop: wave w owns row-pairs (w, w+4); per pair rows (p, p+8) ----
  float T[16];
  #pragma unroll
  for (int z = 0; z < 16; ++z) T[z] = 0.f;

  #pragma unroll
  for (int pp = 0; pp < 2; ++pp) {
    const int p = w + pp * 4;
    const uint32_t jb = (uint32_t)(g0 + p) * 1000u;
    const float* sqL = &sq_s[p * 32];
    const float* sqH = &sq_s[(p + 8) * 32];
    float t0l = 0.f, t1l = 0.f, t2l = 0.f, t3l = 0.f;
    float t0h = 0.f, t1h = 0.f, t2h = 0.f, t3h = 0.f;
    #pragma unroll 2
    for (int it = 0; it < 16; ++it) {
      int c = it * 64 + lane;
      if (c < 1000) {
        uint32_t y0, y1;
        tf2x32(kc0, kc1, jb + (uint32_t)c, jb + (uint32_t)c + 32768000u, y0, y1);
        int d10 = (c * 6554) >> 16;
        int iy  = (c * 656) >> 16;
        int kz  = c - d10 * 10;
        int jx  = d10 - iy * 10;
        float rL = __builtin_amdgcn_rsqf(neglog_u(y0) + 1e-20f);
        float rH = __builtin_amdgcn_rsqf(neglog_u(y1) + 1e-20f);
        float wL = sqL[jx] * sqL[10 + iy] * (sqL[20 + kz] * rL);
        float wH = sqH[jx] * sqH[10 + iy] * (sqH[20 + kz] * rH);
        float fj = (float)jx, fi = (float)iy, fk = (float)kz;
        t0l += wL; t1l += wL * fj; t2l += wL * fi; t3l += wL * fk;
        t0h += wH; t1h += wH * fj; t2h += wH * fi; t3h += wH * fk;
      }
    }
    T[pp * 8 + 0] = t0l; T[pp * 8 + 1] = t1l; T[pp * 8 + 2] = t2l; T[pp * 8 + 3] = t3l;
    T[pp * 8 + 4] = t0h; T[pp * 8 + 5] = t1h; T[pp * 8 + 6] = t2h; T[pp * 8 + 7] = t3h;
  }

  // ---- butterfly-reduce all 16 accumulators across the wave ----
  #pragma unroll
  for (int off = 32; off > 0; off >>= 1) {
    #pragma unroll
    for (int z = 0; z < 16; ++z) T[z] += __shfl_xor(T[z], off);
  }
  if (lane == 0) {
    #pragma unroll
    for (int pp = 0; pp < 2; ++pp) {
      int rl = w + pp * 4, rh = rl + 8;
      #pragma unroll
      for (int cmp = 0; cmp < 4; ++cmp) {
        tq_s[rl * 4 + cmp] = T[pp * 8 + cmp];
        tq_s[rh * 4 + cmp] = T[pp * 8 + 4 + cmp];
      }
    }
  }
  __syncthreads();

  // ---- qc epilogue: rank-4 reconstruction, fp32 throughout ----
  {
    const int d = t & 63, rb = t >> 6;
    const float l0 = lw[d * 3 + 0], l1 = lw[d * 3 + 1], l2 = lw[d * 3 + 2];
    const float lbd = lb[d];
    const float stepf = (float)(1.5 / 9.0);
    #pragma unroll
    for (int kk = 0; kk < 4; ++kk) {
      int m = rb + kk * 4;
      float T0v = tq_s[m * 4 + 0], T1v = tq_s[m * 4 + 1];
      float T2v = tq_s[m * 4 + 2], T3v = tq_s[m * 4 + 3];
      float num = (T1v * l0 + T2v * l1 + T3v * l2) * stepf + T0v * lbd;
      int grow = (m < 8) ? (g0 + m) : (g0 + m - 8 + NROWS_HALF);
      out[QC_OFF + grow * 64 + d] = num * __builtin_amdgcn_rcpf(T0v);
    }
  }

  // ---- 5b: per (pair p, k) codebook path; 8 lanes per wave (32 units) ----
  float* q_s = x_s;   // x dead (frags extracted pre-loop)
  if (lane < 8) {
    const int u_ = w * 8 + lane;
    const int p = u_ >> 2, k = u_ & 3;
    const int rA = p, rB = p + 8;
    float xpA[8], xpB[8];
    #pragma unroll
    for (int n = 0; n < 8; ++n) {
      xpA[n] = xp_s[rA * 32 + k * 8 + n];
      xpB[n] = xp_s[rB * 32 + k * 8 + n];
    }
    float mA = xpA[0], mB = xpB[0];
    #pragma unroll
    for (int n = 1; n < 8; ++n) { mA = fmaxf(mA, xpA[n]); mB = fmaxf(mB, xpB[n]); }
    const uint32_t base = (uint32_t)(g0 + p) * 32u + (uint32_t)k * 8u;
    float s0A = 0.f, s1A = 0.f, s0B = 0.f, s1B = 0.f, swA = 0.f, swB = 0.f;
    float wvA[8], wvB[8];
    #pragma unroll
    for (int n = 0; n < 8; ++n) {
      float eA = __builtin_amdgcn_exp2f(xpA[n] - mA);
      float eB = __builtin_amdgcn_exp2f(xpB[n] - mB);
      s0A += eA; s1A += eA * xpA[n];
      s0B += eB; s1B += eB * xpB[n];
      uint32_t y0, y1;
      tf2x32(kp0, kp1, base + n, base + n + 1048576u, y0, y1);
      wvA[n] = __builtin_amdgcn_exp2f((xpA[n] - mA) * 0.5f) *
               __builtin_amdgcn_rsqf(neglog_u(y0) + 1e-20f);
      wvB[n] = __builtin_amdgcn_exp2f((xpB[n] - mB) * 0.5f) *
               __builtin_amdgcn_rsqf(neglog_u(y1) + 1e-20f);
      swA += wvA[n]; swB += wvB[n];
    }
    atomicAdd(&kl_s,
        LN2 * ((s1A * __builtin_amdgcn_rcpf(s0A) - mA) - __builtin_amdgcn_logf(s0A)) +
        LN2 * ((s1B * __builtin_amdgcn_rcpf(s0B) - mB) - __builtin_amdgcn_logf(s0B)) +
        4.1588830833596715f);
    float invA = __builtin_amdgcn_rcpf(swA), invB = __builtin_amdgcn_rcpf(swB);
    #pragma unroll
    for (int e = 0; e < 16; ++e) {
      float aA = 0.f, aB = 0.f;
      #pragma unroll
      for (int n = 0; n < 8; ++n) {
        float ev = emb[(k * 8 + n) * 16 + e];
        aA += wvA[n] * ev; aB += wvB[n] * ev;
      }
      q_s[rA * X_STRIDE + k * 16 + e] = aA * invA;
      q_s[rB * X_STRIDE + k * 16 + e] = aB * invB;
    }
  }
  __syncthreads();

  // ---- copyout quantized (coalesced) + loss; last block finalizes loss ----
  #pragma unroll
  for (int it = 0; it < 4; ++it) {
    int idx = it * 256 + t;
    int rl = idx >> 6, c = idx & 63;
    int row = (rl < 8) ? (g0 + rl) : (g0 + rl - 8 + NROWS_HALF);
    out[row * 64 + c] = q_s[rl * X_STRIDE + c];
  }
  if (t == 0) {
    atomicAdd(loss_acc, kl_s);
    __threadfence();
    uint32_t tk = atomicAdd(&g_ticket, 1u);
    if (tk == 4095u) {
      __threadfence();
      out[LOSS_OFF] = atomicAdd(loss_acc, 0.0f) * 0.2f;
    }
  }
}

extern "C" void kernel_launch(void* const* d_in, const int* in_sizes, int n_in,
                              void* d_out, int out_size, void* d_ws, size_t ws_size,
                              hipStream_t stream) {
  const float* inp  = (const float*)d_in[0];   // [32,2048,64]
  const float* lw   = (const float*)d_in[1];   // [64,3]
  const float* lb   = (const float*)d_in[2];   // [64]
  const float* emb  = (const float*)d_in[3];   // [32,16] normalized
  const float* lws  = (const float*)d_in[4];   // [4,16,64]
  float* out = (float*)d_out;
  ushort* wsu = (ushort*)d_ws;
  float* loss = (float*)((char*)d_ws + WS_LOSS_BYTE);

  // JAX PRNG keys: key(42) -> [0,42]; split = threefry over iota(4)
  uint32_t a0, b0, a1, b1;
  tf2x32(0u, 42u, 0u, 2u, a0, b0);
  tf2x32(0u, 42u, 1u, 3u, a1, b1);
  const uint32_t kc0 = a0, kc1 = a1;   // coord-noise key
  const uint32_t kp0 = b0, kp1 = b1;   // codebook-noise key

  setup_kernel<<<9, 256, 0, stream>>>(emb, lws, wsu);
  fused_kernel<<<4096, 256, 0, stream>>>(inp, emb, lw, lb, wsu, out, loss,
                                         kc0, kc1, kp0, kp1);
}

// Round 8
// 231.797 us; speedup vs baseline: 1.5825x; 1.0887x over previous
//
#include <hip/hip_runtime.h>
#include <cstdint>

#define NROWS_HALF 32768
#define QC_OFF 4194304            // quantized_coord offset in d_out (floats)
#define LOSS_OFF 8388608          // loss offset in d_out (floats)

// ws layout (ushort units): CODE_HI [32][64] at 0, CODE_LO [32][64] at 2048
// (code m rows = emb[m] @ lws[k], scaled by log2e, split bf16 hi/lo).
// fp32 loss accumulator at byte 8192.
#define U_CH 0
#define U_CL 2048
#define WS_LOSS_BYTE 8192

#define X_STRIDE 68
#define LOG2E 1.4426950408889634f
#define LN2   0.6931471805599453f

typedef short short8 __attribute__((ext_vector_type(8)));
typedef float float4v __attribute__((ext_vector_type(4)));

#define MFMA16(a, b, c) __builtin_amdgcn_mfma_f32_16x16x32_bf16((a), (b), (c), 0, 0, 0)

__device__ uint32_t g_ticket;     // block-completion ticket (zeroed by setup each launch)

// ---------------- Threefry-2x32 (20 rounds), matches JAX ----------------
__host__ __device__ __forceinline__ void tf2x32(uint32_t k0, uint32_t k1,
                                                uint32_t x0, uint32_t x1,
                                                uint32_t& o0, uint32_t& o1) {
  const uint32_t k2 = k0 ^ k1 ^ 0x1BD11BDAu;
#define TF_R(r) { x0 += x1; x1 = (x1 << (r)) | (x1 >> (32 - (r))); x1 ^= x0; }
  x0 += k0; x1 += k1;
  TF_R(13) TF_R(15) TF_R(26) TF_R(6)
  x0 += k1; x1 += k2 + 1u;
  TF_R(17) TF_R(29) TF_R(16) TF_R(24)
  x0 += k2; x1 += k0 + 2u;
  TF_R(13) TF_R(15) TF_R(26) TF_R(6)
  x0 += k0; x1 += k1 + 3u;
  TF_R(17) TF_R(29) TF_R(16) TF_R(24)
  x0 += k1; x1 += k2 + 4u;
  TF_R(13) TF_R(15) TF_R(26) TF_R(6)
  x0 += k2; x1 += k0 + 5u;
#undef TF_R
  o0 = x0; o1 = x1;
}

// neglog_u(bits) = -log(u + 1e-20), u = (bits>>9 | 1.0f) - 1.0f.
// exp(gumbel/2) == rsqrt(neglog_u + 1e-20) exactly (gumbel = -log(-log(u+e)+e)).
__device__ __forceinline__ float neglog_u(uint32_t bits) {
  const uint32_t mant = bits >> 9;
  const float u = __uint_as_float(mant | 0x3f800000u) - 1.0f;
  const float delta = (float)(8388608u - mant) * 1.1920928955078125e-7f;
  float nl;
  if (delta < 0.00390625f) {
    nl = delta + 0.5f * delta * delta + 0.33333333f * delta * delta * delta;
  } else {
    nl = -LN2 * __builtin_amdgcn_logf(u + 1e-20f);
  }
  return nl;
}

// round-to-nearest-even bf16 (returns 16-bit pattern in low bits)
__device__ __forceinline__ uint32_t rn16(float f) {
  uint32_t u = __float_as_uint(f);
  return (u + 0x7FFFu + ((u >> 16) & 1u)) >> 16;
}

__device__ __forceinline__ void split2_rn(float f0, float f1, uint32_t& hi, uint32_t& lo) {
  uint32_t h0 = rn16(f0), h1 = rn16(f1);
  hi = h0 | (h1 << 16);
  float l0 = f0 - __uint_as_float(h0 << 16);
  float l1 = f1 - __uint_as_float(h1 << 16);
  lo = rn16(l0) | (rn16(l1) << 16);
}

__device__ __forceinline__ void split8_rn(const float* p, short8& hi, short8& lo) {
  float4 f0 = *(const float4*)p;
  float4 f1 = *(const float4*)(p + 4);
  union { uint32_t u[4]; short8 s; } H, L;
  split2_rn(f0.x, f0.y, H.u[0], L.u[0]);
  split2_rn(f0.z, f0.w, H.u[1], L.u[1]);
  split2_rn(f1.x, f1.y, H.u[2], L.u[2]);
  split2_rn(f1.z, f1.w, H.u[3], L.u[3]);
  hi = H.s; lo = L.s;
}

__device__ __forceinline__ short8 as_s8(uint4 v) {
  union { uint4 u; short8 s; } c; c.u = v; return c.s;
}

// one 16-col tile of xp: 3-MFMA split-bf16 (hi+lo), B rows nb..nb+15
__device__ __forceinline__ float4v tile_mfma(const ushort* __restrict__ Vh,
                                             const ushort* __restrict__ Vl,
                                             int nb, const short8* ah, const short8* al) {
  uint4 bh0 = *(const uint4*)(Vh + nb);
  uint4 bl0 = *(const uint4*)(Vl + nb);
  float4v acc = {0.f, 0.f, 0.f, 0.f};
  acc = MFMA16(ah[0], as_s8(bh0), acc);
  acc = MFMA16(ah[0], as_s8(bl0), acc);
  acc = MFMA16(al[0], as_s8(bh0), acc);
  uint4 bh1 = *(const uint4*)(Vh + nb + 32);
  uint4 bl1 = *(const uint4*)(Vl + nb + 32);
  acc = MFMA16(ah[1], as_s8(bh1), acc);
  acc = MFMA16(ah[1], as_s8(bl1), acc);
  acc = MFMA16(al[1], as_s8(bh1), acc);
  return acc;
}

// ---------------- setup: compact code table + loss/ticket=0 ----------------
__global__ void setup_kernel(const float* __restrict__ emb, const float* __restrict__ lws,
                             ushort* __restrict__ wsu) {
  int idx = blockIdx.x * 256 + threadIdx.x;
  if (idx < 2048) {
    int m = idx >> 6, c = idx & 63, k = m >> 3;
    float a = 0.f;
    #pragma unroll
    for (int e = 0; e < 16; ++e) a += emb[m * 16 + e] * lws[(k * 16 + e) * 64 + c];
    a *= LOG2E;                      // xp logits in log2 domain
    uint32_t h = rn16(a);
    float fl = a - __uint_as_float(h << 16);
    wsu[U_CH + idx] = (ushort)h;
    wsu[U_CL + idx] = (ushort)rn16(fl);
  } else if (idx == 2048) {
    *(float*)((char*)wsu + WS_LOSS_BYTE) = 0.f;
    g_ticket = 0u;
  }
}

// ---------------- fused main kernel: 4096 blocks x 256 (4 waves) ----------------
// Separable coordinate path (r7) + this round:
//  - axis tables as float2 (sqrtP, float(i)), padded to 12 slots per axis with
//    zero weight at iy=10/11 so c in [1000,1024) contributes w=0 => branchless loop
//  - 5b codebook path parallelized to all 256 threads (phase A: per (unit,n) lane
//    with 8-lane shfl reduces; phase B: (row,e) reconstruction from LDS)
__global__ __launch_bounds__(256, 4) void fused_kernel(
    const float* __restrict__ inp, const float* __restrict__ emb,
    const float* __restrict__ lw, const float* __restrict__ lb,
    const ushort* __restrict__ wsu, float* __restrict__ out,
    float* __restrict__ loss_acc,
    uint32_t kc0, uint32_t kc1, uint32_t kp0, uint32_t kp1) {

  __shared__ float x_s[16 * X_STRIDE];    // input rows; later q output
  __shared__ float xp_s[16 * 32];         // codebook logits (log2 domain)
  __shared__ float2 sq2_s[16 * 36];       // [row][axis*12+i] = (sqrt(P), float(i))
  __shared__ float u_s[16 * 3];           // per-row u0,u1,u2
  __shared__ float swq_s[96];             // [axis][row][{S,W}]
  __shared__ float tq_s[16 * 4];          // per-row T0..T3
  __shared__ float emb_s[512];            // emb [32][16] staged
  __shared__ float wv_s[512];             // 5b weights [unit(32)][rowhalf(2)][n(8)]
  __shared__ float inv_s[64];             // 5b 1/sum  [unit(32)][rowhalf(2)]
  __shared__ float kl_s;

  const int t = threadIdx.x;
  const int lane = t & 63;
  const int w = t >> 6;                   // 0..3
  const int q = lane >> 4;
  const int mn = lane & 15;
  const int g0 = blockIdx.x * 8;

  if (t == 0) kl_s = 0.f;

  // stage emb (2KB) into LDS
  emb_s[t] = emb[t];
  emb_s[t + 256] = emb[t + 256];

  // per-lane projection coefficients (lane = channel c)
  const float pw0 = lw[lane * 3 + 0];
  const float pw1 = lw[lane * 3 + 1];
  const float pw2 = lw[lane * 3 + 2];

  // ---- load 16 input rows + per-row u = W^T x (3 butterfly reductions) ----
  #pragma unroll
  for (int it = 0; it < 4; ++it) {
    int rl = it * 4 + w;
    int row = (rl < 8) ? (g0 + rl) : (g0 + rl - 8 + NROWS_HALF);
    float v = inp[row * 64 + lane];
    x_s[rl * X_STRIDE + lane] = v;
    float u0 = v * pw0, u1 = v * pw1, u2 = v * pw2;
    #pragma unroll
    for (int off = 32; off > 0; off >>= 1) {
      u0 += __shfl_xor(u0, off);
      u1 += __shfl_xor(u1, off);
      u2 += __shfl_xor(u2, off);
    }
    if (lane == 0) {
      u_s[rl * 3 + 0] = u0; u_s[rl * 3 + 1] = u1; u_s[rl * 3 + 2] = u2;
    }
  }
  __syncthreads();

  // ---- phase2: per (row,axis): P_i = exp2((ua*g_i - 1.5*relu(ua))*log2e) ----
  if (t < 48) {
    const int row = t & 15, axis = t >> 4;
    const float ua = u_s[row * 3 + axis];
    const float b = 1.5f * fmaxf(ua, 0.f);
    float S = 0.f, W = 0.f;
    #pragma unroll
    for (int i = 0; i < 10; ++i) {
      float gi = (float)(i * (1.5 / 9.0));
      float lg = (ua * gi - b) * LOG2E;      // <= 0
      float P = __builtin_amdgcn_exp2f(lg);
      S += P; W += lg * P;
      sq2_s[row * 36 + axis * 12 + i] = make_float2(__builtin_amdgcn_sqrtf(P), (float)i);
    }
    // pad slots (iy=10/11 reachable for c in [1000,1024)): zero weight kills them
    sq2_s[row * 36 + axis * 12 + 10] = make_float2(0.f, 10.f);
    sq2_s[row * 36 + axis * 12 + 11] = make_float2(0.f, 11.f);
    swq_s[axis * 32 + row * 2 + 0] = S;
    swq_s[axis * 32 + row * 2 + 1] = W;
  }

  // ---- A fragments for code tiles (waves 0,3 only) ----
  short8 ah[2], al[2];
  if (w == 0 || w == 3) {
    #pragma unroll
    for (int s = 0; s < 2; ++s)
      split8_rn(&x_s[mn * X_STRIDE + s * 32 + q * 8], ah[s], al[s]);
  }
  __syncthreads();

  // ---- coord KL, closed form per row (t<16) ----
  if (t < 16) {
    float Sa = swq_s[t * 2], Wa = swq_s[t * 2 + 1];
    float Sb = swq_s[32 + t * 2], Wb = swq_s[32 + t * 2 + 1];
    float Sc = swq_s[64 + t * 2], Wc = swq_s[64 + t * 2 + 1];
    float kl = LN2 * ((Wa * __builtin_amdgcn_rcpf(Sa) +
                       Wb * __builtin_amdgcn_rcpf(Sb) +
                       Wc * __builtin_amdgcn_rcpf(Sc)) -
                      __builtin_amdgcn_logf(Sa * Sb * Sc)) + 6.9077552789821f;
    atomicAdd(&kl_s, kl);
  }

  // ---- code tiles: xp logits via compact code table (M rows 0..31) ----
  if (w == 0 || w == 3) {
    const int cti = (w == 0) ? 1 : 0;
    float4v acc = tile_mfma(wsu + U_CH, wsu + U_CL, (cti * 16 + mn) * 64 + q * 8, ah, al);
    #pragma unroll
    for (int r = 0; r < 4; ++r)
      xp_s[(q * 4 + r) * 32 + cti * 16 + mn] = acc[r];
  }

  // ---- main loop: wave w owns row-pairs (w, w+4); per pair rows (p, p+8) ----
  float T[16];
  #pragma unroll
  for (int z = 0; z < 16; ++z) T[z] = 0.f;

  #pragma unroll
  for (int pp = 0; pp < 2; ++pp) {
    const int p = w + pp * 4;
    const uint32_t jb = (uint32_t)(g0 + p) * 1000u;
    const float2* sqL = &sq2_s[p * 36];
    const float2* sqH = &sq2_s[(p + 8) * 36];
    float t0l = 0.f, t1l = 0.f, t2l = 0.f, t3l = 0.f;
    float t0h = 0.f, t1h = 0.f, t2h = 0.f, t3h = 0.f;
    #pragma unroll 2
    for (int it = 0; it < 16; ++it) {
      int c = it * 64 + lane;            // < 1024; pad entries give w = 0
      uint32_t y0, y1;
      tf2x32(kc0, kc1, jb + (uint32_t)c, jb + (uint32_t)c + 32768000u, y0, y1);
      int d10 = (c * 6554) >> 16;
      int iy  = (c * 656) >> 16;
      int kz  = c - d10 * 10;
      int jx  = d10 - iy * 10;
      float2 a2 = sqL[jx], b2 = sqL[12 + iy], c2 = sqL[24 + kz];
      float2 aH = sqH[jx], bH = sqH[12 + iy], cH = sqH[24 + kz];
      float rL = __builtin_amdgcn_rsqf(neglog_u(y0) + 1e-20f);
      float rH = __builtin_amdgcn_rsqf(neglog_u(y1) + 1e-20f);
      float wL = a2.x * b2.x * (c2.x * rL);
      float wH = aH.x * bH.x * (cH.x * rH);
      t0l += wL; t1l += wL * a2.y; t2l += wL * b2.y; t3l += wL * c2.y;
      t0h += wH; t1h += wH * a2.y; t2h += wH * b2.y; t3h += wH * c2.y;
    }
    T[pp * 8 + 0] = t0l; T[pp * 8 + 1] = t1l; T[pp * 8 + 2] = t2l; T[pp * 8 + 3] = t3l;
    T[pp * 8 + 4] = t0h; T[pp * 8 + 5] = t1h; T[pp * 8 + 6] = t2h; T[pp * 8 + 7] = t3h;
  }

  // ---- butterfly-reduce all 16 accumulators across the wave ----
  #pragma unroll
  for (int off = 32; off > 0; off >>= 1) {
    #pragma unroll
    for (int z = 0; z < 16; ++z) T[z] += __shfl_xor(T[z], off);
  }
  if (lane == 0) {
    #pragma unroll
    for (int pp = 0; pp < 2; ++pp) {
      int rl = w + pp * 4, rh = rl + 8;
      #pragma unroll
      for (int cmp = 0; cmp < 4; ++cmp) {
        tq_s[rl * 4 + cmp] = T[pp * 8 + cmp];
        tq_s[rh * 4 + cmp] = T[pp * 8 + 4 + cmp];
      }
    }
  }
  __syncthreads();

  // ---- qc epilogue: rank-4 reconstruction, fp32 throughout ----
  {
    const int d = t & 63, rb = t >> 6;
    const float l0 = lw[d * 3 + 0], l1 = lw[d * 3 + 1], l2 = lw[d * 3 + 2];
    const float lbd = lb[d];
    const float stepf = (float)(1.5 / 9.0);
    #pragma unroll
    for (int kk = 0; kk < 4; ++kk) {
      int m = rb + kk * 4;
      float T0v = tq_s[m * 4 + 0], T1v = tq_s[m * 4 + 1];
      float T2v = tq_s[m * 4 + 2], T3v = tq_s[m * 4 + 3];
      float num = (T1v * l0 + T2v * l1 + T3v * l2) * stepf + T0v * lbd;
      int grow = (m < 8) ? (g0 + m) : (g0 + m - 8 + NROWS_HALF);
      out[QC_OFF + grow * 64 + d] = num * __builtin_amdgcn_rcpf(T0v);
    }
  }

  // ---- 5b phase A: all 256 threads; lane = (unit u, element n) ----
  {
    const int u_ = t >> 3, n = t & 7;      // u_ 0..31
    const int p = u_ >> 2, k = u_ & 3;
    const float xpA = xp_s[p * 32 + k * 8 + n];
    const float xpB = xp_s[(p + 8) * 32 + k * 8 + n];
    float mA = xpA, mB = xpB;
    #pragma unroll
    for (int off = 1; off < 8; off <<= 1) {
      mA = fmaxf(mA, __shfl_xor(mA, off));
      mB = fmaxf(mB, __shfl_xor(mB, off));
    }
    float eA = __builtin_amdgcn_exp2f(xpA - mA);
    float eB = __builtin_amdgcn_exp2f(xpB - mB);
    float s0A = eA, s1A = eA * xpA, s0B = eB, s1B = eB * xpB;
    const uint32_t base = (uint32_t)(g0 + p) * 32u + (uint32_t)k * 8u;
    uint32_t y0, y1;
    tf2x32(kp0, kp1, base + (uint32_t)n, base + (uint32_t)n + 1048576u, y0, y1);
    float wvA = __builtin_amdgcn_exp2f((xpA - mA) * 0.5f) *
                __builtin_amdgcn_rsqf(neglog_u(y0) + 1e-20f);
    float wvB = __builtin_amdgcn_exp2f((xpB - mB) * 0.5f) *
                __builtin_amdgcn_rsqf(neglog_u(y1) + 1e-20f);
    float swA = wvA, swB = wvB;
    #pragma unroll
    for (int off = 1; off < 8; off <<= 1) {
      s0A += __shfl_xor(s0A, off);
      s1A += __shfl_xor(s1A, off);
      s0B += __shfl_xor(s0B, off);
      s1B += __shfl_xor(s1B, off);
      swA += __shfl_xor(swA, off);
      swB += __shfl_xor(swB, off);
    }
    wv_s[u_ * 16 + n] = wvA;
    wv_s[u_ * 16 + 8 + n] = wvB;
    if (n == 0) {
      inv_s[u_ * 2 + 0] = __builtin_amdgcn_rcpf(swA);
      inv_s[u_ * 2 + 1] = __builtin_amdgcn_rcpf(swB);
      atomicAdd(&kl_s,
          LN2 * ((s1A * __builtin_amdgcn_rcpf(s0A) - mA) - __builtin_amdgcn_logf(s0A)) +
          LN2 * ((s1B * __builtin_amdgcn_rcpf(s0B) - mB) - __builtin_amdgcn_logf(s0B)) +
          4.1588830833596715f);
    }
  }
  __syncthreads();

  // ---- 5b phase B: thread = (row r, dim e); q = sum_n wv*emb / sum ----
  float* q_s = x_s;   // x dead (frags extracted pre-loop)
  {
    const int r = t >> 4, e = t & 15;
    const int p = r & 7, h = r >> 3;
    #pragma unroll
    for (int k = 0; k < 4; ++k) {
      const int u_ = p * 4 + k;
      float aa = 0.f;
      #pragma unroll
      for (int n = 0; n < 8; ++n)
        aa += wv_s[u_ * 16 + h * 8 + n] * emb_s[(k * 8 + n) * 16 + e];
      q_s[r * X_STRIDE + k * 16 + e] = aa * inv_s[u_ * 2 + h];
    }
  }
  __syncthreads();

  // ---- copyout quantized (coalesced) + loss; last block finalizes loss ----
  #pragma unroll
  for (int it = 0; it < 4; ++it) {
    int idx = it * 256 + t;
    int rl = idx >> 6, c = idx & 63;
    int row = (rl < 8) ? (g0 + rl) : (g0 + rl - 8 + NROWS_HALF);
    out[row * 64 + c] = q_s[rl * X_STRIDE + c];
  }
  if (t == 0) {
    atomicAdd(loss_acc, kl_s);
    __threadfence();
    uint32_t tk = atomicAdd(&g_ticket, 1u);
    if (tk == 4095u) {
      __threadfence();
      out[LOSS_OFF] = atomicAdd(loss_acc, 0.0f) * 0.2f;
    }
  }
}

extern "C" void kernel_launch(void* const* d_in, const int* in_sizes, int n_in,
                              void* d_out, int out_size, void* d_ws, size_t ws_size,
                              hipStream_t stream) {
  const float* inp  = (const float*)d_in[0];   // [32,2048,64]
  const float* lw   = (const float*)d_in[1];   // [64,3]
  const float* lb   = (const float*)d_in[2];   // [64]
  const float* emb  = (const float*)d_in[3];   // [32,16] normalized
  const float* lws  = (const float*)d_in[4];   // [4,16,64]
  float* out = (float*)d_out;
  ushort* wsu = (ushort*)d_ws;
  float* loss = (float*)((char*)d_ws + WS_LOSS_BYTE);

  // JAX PRNG keys: key(42) -> [0,42]; split = threefry over iota(4)
  uint32_t a0, b0, a1, b1;
  tf2x32(0u, 42u, 0u, 2u, a0, b0);
  tf2x32(0u, 42u, 1u, 3u, a1, b1);
  const uint32_t kc0 = a0, kc1 = a1;   // coord-noise key
  const uint32_t kp0 = b0, kp1 = b1;   // codebook-noise key

  setup_kernel<<<9, 256, 0, stream>>>(emb, lws, wsu);
  fused_kernel<<<4096, 256, 0, stream>>>(inp, emb, lw, lb, wsu, out, loss,
                                         kc0, kc1, kp0, kp1);
}

// Round 9
// 219.821 us; speedup vs baseline: 1.6687x; 1.0545x over previous
//
#include <hip/hip_runtime.h>
#include <cstdint>

#define NROWS_HALF 32768
#define QC_OFF 4194304            // quantized_coord offset in d_out (floats)
#define LOSS_OFF 8388608          // loss offset in d_out (floats)

// ws layout (ushort units): CODE_HI [32][64] at 0, CODE_LO [32][64] at 2048
// (code m rows = emb[m] @ lws[k], scaled by log2e, split bf16 hi/lo).
// fp32 loss accumulator at byte 8192.
#define U_CH 0
#define U_CL 2048
#define WS_LOSS_BYTE 8192

#define X_STRIDE 68
#define LOG2E 1.4426950408889634f
#define LN2   0.6931471805599453f

typedef short short8 __attribute__((ext_vector_type(8)));
typedef float float4v __attribute__((ext_vector_type(4)));

#define MFMA16(a, b, c) __builtin_amdgcn_mfma_f32_16x16x32_bf16((a), (b), (c), 0, 0, 0)

__device__ uint32_t g_ticket;     // block-completion ticket (zeroed by setup each launch)

// ---------------- Threefry-2x32 (20 rounds), matches JAX ----------------
__host__ __device__ __forceinline__ void tf2x32(uint32_t k0, uint32_t k1,
                                                uint32_t x0, uint32_t x1,
                                                uint32_t& o0, uint32_t& o1) {
  const uint32_t k2 = k0 ^ k1 ^ 0x1BD11BDAu;
#define TF_R(r) { x0 += x1; x1 = (x1 << (r)) | (x1 >> (32 - (r))); x1 ^= x0; }
  x0 += k0; x1 += k1;
  TF_R(13) TF_R(15) TF_R(26) TF_R(6)
  x0 += k1; x1 += k2 + 1u;
  TF_R(17) TF_R(29) TF_R(16) TF_R(24)
  x0 += k2; x1 += k0 + 2u;
  TF_R(13) TF_R(15) TF_R(26) TF_R(6)
  x0 += k0; x1 += k1 + 3u;
  TF_R(17) TF_R(29) TF_R(16) TF_R(24)
  x0 += k1; x1 += k2 + 4u;
  TF_R(13) TF_R(15) TF_R(26) TF_R(6)
  x0 += k2; x1 += k0 + 5u;
#undef TF_R
  o0 = x0; o1 = x1;
}

// rsq_neglog2(bits) = rsqrt(max(-log2(u + 1e-20), 1e-20)), u = (bits>>9|1.0)-1.
// Equals exp(gumbel/2) up to a UNIFORM factor 1/sqrt(ln2), which cancels in
// every consumer (all weights are normalized by sums of same-scaled weights).
// v_log_f32 is <=1 ulp relative, so no series branch is needed near u->1;
// the fmax floor guards a possible exact-zero return.
__device__ __forceinline__ float rsq_neglog2(uint32_t bits) {
  const float u = __uint_as_float((bits >> 9) | 0x3f800000u) - 1.0f;
  const float l2 = __builtin_amdgcn_logf(u + 1e-20f);   // log2
  return __builtin_amdgcn_rsqf(fmaxf(-l2, 1e-20f));
}

// round-to-nearest-even bf16 (returns 16-bit pattern in low bits)
__device__ __forceinline__ uint32_t rn16(float f) {
  uint32_t u = __float_as_uint(f);
  return (u + 0x7FFFu + ((u >> 16) & 1u)) >> 16;
}

__device__ __forceinline__ void split2_rn(float f0, float f1, uint32_t& hi, uint32_t& lo) {
  uint32_t h0 = rn16(f0), h1 = rn16(f1);
  hi = h0 | (h1 << 16);
  float l0 = f0 - __uint_as_float(h0 << 16);
  float l1 = f1 - __uint_as_float(h1 << 16);
  lo = rn16(l0) | (rn16(l1) << 16);
}

__device__ __forceinline__ void split8_rn(const float* p, short8& hi, short8& lo) {
  float4 f0 = *(const float4*)p;
  float4 f1 = *(const float4*)(p + 4);
  union { uint32_t u[4]; short8 s; } H, L;
  split2_rn(f0.x, f0.y, H.u[0], L.u[0]);
  split2_rn(f0.z, f0.w, H.u[1], L.u[1]);
  split2_rn(f1.x, f1.y, H.u[2], L.u[2]);
  split2_rn(f1.z, f1.w, H.u[3], L.u[3]);
  hi = H.s; lo = L.s;
}

__device__ __forceinline__ short8 as_s8(uint4 v) {
  union { uint4 u; short8 s; } c; c.u = v; return c.s;
}

// one 16-col tile of xp: 3-MFMA split-bf16 (hi+lo), B rows nb..nb+15
__device__ __forceinline__ float4v tile_mfma(const ushort* __restrict__ Vh,
                                             const ushort* __restrict__ Vl,
                                             int nb, const short8* ah, const short8* al) {
  uint4 bh0 = *(const uint4*)(Vh + nb);
  uint4 bl0 = *(const uint4*)(Vl + nb);
  float4v acc = {0.f, 0.f, 0.f, 0.f};
  acc = MFMA16(ah[0], as_s8(bh0), acc);
  acc = MFMA16(ah[0], as_s8(bl0), acc);
  acc = MFMA16(al[0], as_s8(bh0), acc);
  uint4 bh1 = *(const uint4*)(Vh + nb + 32);
  uint4 bl1 = *(const uint4*)(Vl + nb + 32);
  acc = MFMA16(ah[1], as_s8(bh1), acc);
  acc = MFMA16(ah[1], as_s8(bl1), acc);
  acc = MFMA16(al[1], as_s8(bh1), acc);
  return acc;
}

// ---------------- setup: compact code table + loss/ticket=0 ----------------
__global__ void setup_kernel(const float* __restrict__ emb, const float* __restrict__ lws,
                             ushort* __restrict__ wsu) {
  int idx = blockIdx.x * 256 + threadIdx.x;
  if (idx < 2048) {
    int m = idx >> 6, c = idx & 63, k = m >> 3;
    float a = 0.f;
    #pragma unroll
    for (int e = 0; e < 16; ++e) a += emb[m * 16 + e] * lws[(k * 16 + e) * 64 + c];
    a *= LOG2E;                      // xp logits in log2 domain
    uint32_t h = rn16(a);
    float fl = a - __uint_as_float(h << 16);
    wsu[U_CH + idx] = (ushort)h;
    wsu[U_CL + idx] = (ushort)rn16(fl);
  } else if (idx == 2048) {
    *(float*)((char*)wsu + WS_LOSS_BYTE) = 0.f;
    g_ticket = 0u;
  }
}

// ---------------- fused main kernel: 2048 blocks x 512 (8 waves, 32 rows) --------
// Separable coordinate path. This round:
//  - 512-thread blocks (32 rows): r1 showed 512-thread blocks reach ~87% occupancy
//    vs the stubborn ~41-46% of every 256-thread build. launch_bounds(512,4) so the
//    allocator is NOT register-squeezed (r1 lesson).
//  - gumbel = 7 instrs: rsqrt(-log2(u+eps)); the 1/sqrt(ln2) scale cancels in all
//    normalizations; no series branch (v_log is 1-ulp relative).
//  - per-pair float4 tables {sqPL, idx, sqPH, idx}: 3 ds_read_b128/iter (was 6 b64).
__global__ __launch_bounds__(512, 4) void fused_kernel(
    const float* __restrict__ inp, const float* __restrict__ emb,
    const float* __restrict__ lw, const float* __restrict__ lb,
    const ushort* __restrict__ wsu, float* __restrict__ out,
    float* __restrict__ loss_acc,
    uint32_t kc0, uint32_t kc1, uint32_t kp0, uint32_t kp1) {

  __shared__ float x_s[32 * X_STRIDE];    // input rows; later q output
  __shared__ float xp_s[32 * 32];         // codebook logits (log2 domain)
  __shared__ float4 sq4_s[16 * 3 * 12];   // [pair][axis][i] = {sqPL, i, sqPH, i}
  __shared__ float u_s[32 * 3];           // per-row u0,u1,u2
  __shared__ float swq_s[192];            // [axis][row][{S,W}]
  __shared__ float tq_s[32 * 4];          // per-row T0..T3
  __shared__ float emb_s[512];            // emb [32][16] staged
  __shared__ float wv_s[64 * 16];         // 5b weights [unit(64)][half(2)][n(8)]
  __shared__ float inv_s[128];            // 5b 1/sum  [unit(64)][half(2)]
  __shared__ float kl_s;

  const int t = threadIdx.x;
  const int lane = t & 63;
  const int w = t >> 6;                   // 0..7
  const int q = lane >> 4;
  const int mn = lane & 15;
  const int g0 = blockIdx.x * 16;

  if (t == 0) kl_s = 0.f;
  emb_s[t] = emb[t];                      // 512 floats, one per thread

  // per-lane projection coefficients (lane = channel c)
  const float pw0 = lw[lane * 3 + 0];
  const float pw1 = lw[lane * 3 + 1];
  const float pw2 = lw[lane * 3 + 2];

  // ---- load 32 input rows + per-row u = W^T x (3 butterfly reductions) ----
  #pragma unroll
  for (int it = 0; it < 4; ++it) {
    int rl = it * 8 + w;
    int row = (rl < 16) ? (g0 + rl) : (g0 + rl - 16 + NROWS_HALF);
    float v = inp[row * 64 + lane];
    x_s[rl * X_STRIDE + lane] = v;
    float u0 = v * pw0, u1 = v * pw1, u2 = v * pw2;
    #pragma unroll
    for (int off = 32; off > 0; off >>= 1) {
      u0 += __shfl_xor(u0, off);
      u1 += __shfl_xor(u1, off);
      u2 += __shfl_xor(u2, off);
    }
    if (lane == 0) {
      u_s[rl * 3 + 0] = u0; u_s[rl * 3 + 1] = u1; u_s[rl * 3 + 2] = u2;
    }
  }
  __syncthreads();

  // ---- phase2: per (row,axis): P_i = exp2((ua*g_i - 1.5*relu(ua))*log2e) ----
  if (t < 96) {
    const int row = t & 31, axis = t >> 5;
    const int pair = row & 15, half = row >> 4;
    const float ua = u_s[row * 3 + axis];
    const float b = 1.5f * fmaxf(ua, 0.f);
    float S = 0.f, W = 0.f;
    float2* slotbase = (float2*)&sq4_s[(pair * 3 + axis) * 12];
    #pragma unroll
    for (int i = 0; i < 10; ++i) {
      float gi = (float)(i * (1.5 / 9.0));
      float lg = (ua * gi - b) * LOG2E;      // <= 0
      float P = __builtin_amdgcn_exp2f(lg);
      S += P; W += lg * P;
      slotbase[i * 2 + half] = make_float2(__builtin_amdgcn_sqrtf(P), (float)i);
    }
    // pad slots (iy=10/11 reachable for c in [1000,1024)): zero weight kills them
    slotbase[10 * 2 + half] = make_float2(0.f, 10.f);
    slotbase[11 * 2 + half] = make_float2(0.f, 11.f);
    swq_s[axis * 64 + row * 2 + 0] = S;
    swq_s[axis * 64 + row * 2 + 1] = W;
  }

  // ---- A fragments for code tiles (waves 0,1,6,7; row-tile rt, code-tile ct) ----
  short8 ah[2], al[2];
  const bool codew = (w < 2) || (w >= 6);
  const int rt = (w >= 6) ? 1 : 0;
  const int ct = (w < 2) ? w : (w - 6);
  if (codew) {
    #pragma unroll
    for (int s = 0; s < 2; ++s)
      split8_rn(&x_s[(rt * 16 + mn) * X_STRIDE + s * 32 + q * 8], ah[s], al[s]);
  }
  __syncthreads();

  // ---- coord KL, closed form per row (t<32) ----
  if (t < 32) {
    float Sa = swq_s[t * 2],       Wa = swq_s[t * 2 + 1];
    float Sb = swq_s[64 + t * 2],  Wb = swq_s[64 + t * 2 + 1];
    float Sc = swq_s[128 + t * 2], Wc = swq_s[128 + t * 2 + 1];
    float kl = LN2 * ((Wa * __builtin_amdgcn_rcpf(Sa) +
                       Wb * __builtin_amdgcn_rcpf(Sb) +
                       Wc * __builtin_amdgcn_rcpf(Sc)) -
                      __builtin_amdgcn_logf(Sa * Sb * Sc)) + 6.9077552789821f;
    atomicAdd(&kl_s, kl);
  }

  // ---- code tiles: xp logits via compact code table (M rows 0..31) ----
  if (codew) {
    float4v acc = tile_mfma(wsu + U_CH, wsu + U_CL, (ct * 16 + mn) * 64 + q * 8, ah, al);
    #pragma unroll
    for (int r = 0; r < 4; ++r)
      xp_s[(rt * 16 + q * 4 + r) * 32 + ct * 16 + mn] = acc[r];
  }

  // ---- main loop: wave w owns pairs (w, w+8); pair p = rows (p, p+16) ----
  float T[16];
  #pragma unroll
  for (int z = 0; z < 16; ++z) T[z] = 0.f;

  #pragma unroll
  for (int pp = 0; pp < 2; ++pp) {
    const int p = w + pp * 8;
    const uint32_t jb = (uint32_t)(g0 + p) * 1000u;
    const float4* base4 = &sq4_s[p * 36];
    float t0l = 0.f, t1l = 0.f, t2l = 0.f, t3l = 0.f;
    float t0h = 0.f, t1h = 0.f, t2h = 0.f, t3h = 0.f;
    #pragma unroll 2
    for (int it = 0; it < 16; ++it) {
      int c = it * 64 + lane;            // < 1024; pad entries give w = 0
      uint32_t y0, y1;
      tf2x32(kc0, kc1, jb + (uint32_t)c, jb + (uint32_t)c + 32768000u, y0, y1);
      int d10 = (c * 6554) >> 16;
      int iy  = (c * 656) >> 16;
      int kz  = c - d10 * 10;
      int jx  = d10 - iy * 10;
      float4 a4 = base4[jx], b4 = base4[12 + iy], c4 = base4[24 + kz];
      float rL = rsq_neglog2(y0);
      float rH = rsq_neglog2(y1);
      float wL = a4.x * b4.x * (c4.x * rL);
      float wH = a4.z * b4.z * (c4.z * rH);
      t0l += wL; t1l += wL * a4.y; t2l += wL * b4.y; t3l += wL * c4.y;
      t0h += wH; t1h += wH * a4.y; t2h += wH * b4.y; t3h += wH * c4.y;
    }
    T[pp * 8 + 0] = t0l; T[pp * 8 + 1] = t1l; T[pp * 8 + 2] = t2l; T[pp * 8 + 3] = t3l;
    T[pp * 8 + 4] = t0h; T[pp * 8 + 5] = t1h; T[pp * 8 + 6] = t2h; T[pp * 8 + 7] = t3h;
  }

  // ---- butterfly-reduce all 16 accumulators across the wave ----
  #pragma unroll
  for (int off = 32; off > 0; off >>= 1) {
    #pragma unroll
    for (int z = 0; z < 16; ++z) T[z] += __shfl_xor(T[z], off);
  }
  if (lane == 0) {
    #pragma unroll
    for (int pp = 0; pp < 2; ++pp) {
      int rl = w + pp * 8, rh = rl + 16;
      #pragma unroll
      for (int cmp = 0; cmp < 4; ++cmp) {
        tq_s[rl * 4 + cmp] = T[pp * 8 + cmp];
        tq_s[rh * 4 + cmp] = T[pp * 8 + 4 + cmp];
      }
    }
  }
  __syncthreads();

  // ---- qc epilogue: rank-4 reconstruction, fp32 throughout ----
  {
    const int d = t & 63, rb = t >> 6;     // rb 0..7
    const float l0 = lw[d * 3 + 0], l1 = lw[d * 3 + 1], l2 = lw[d * 3 + 2];
    const float lbd = lb[d];
    const float stepf = (float)(1.5 / 9.0);
    #pragma unroll
    for (int kk = 0; kk < 4; ++kk) {
      int m = rb + kk * 8;                 // 0..31
      float T0v = tq_s[m * 4 + 0], T1v = tq_s[m * 4 + 1];
      float T2v = tq_s[m * 4 + 2], T3v = tq_s[m * 4 + 3];
      float num = (T1v * l0 + T2v * l1 + T3v * l2) * stepf + T0v * lbd;
      int grow = (m < 16) ? (g0 + m) : (g0 + m - 16 + NROWS_HALF);
      out[QC_OFF + grow * 64 + d] = num * __builtin_amdgcn_rcpf(T0v);
    }
  }

  // ---- 5b phase A: one thread per (unit u_, element n); 64 units x 8 ----
  {
    const int u_ = t >> 3, n = t & 7;      // u_ 0..63
    const int p = u_ >> 2, k = u_ & 3;     // p 0..15
    const float xpA = xp_s[p * 32 + k * 8 + n];
    const float xpB = xp_s[(p + 16) * 32 + k * 8 + n];
    float mA = xpA, mB = xpB;
    #pragma unroll
    for (int off = 1; off < 8; off <<= 1) {
      mA = fmaxf(mA, __shfl_xor(mA, off));
      mB = fmaxf(mB, __shfl_xor(mB, off));
    }
    float eA = __builtin_amdgcn_exp2f(xpA - mA);
    float eB = __builtin_amdgcn_exp2f(xpB - mB);
    float s0A = eA, s1A = eA * xpA, s0B = eB, s1B = eB * xpB;
    const uint32_t base = (uint32_t)(g0 + p) * 32u + (uint32_t)k * 8u;
    uint32_t y0, y1;
    tf2x32(kp0, kp1, base + (uint32_t)n, base + (uint32_t)n + 1048576u, y0, y1);
    float wvA = __builtin_amdgcn_exp2f((xpA - mA) * 0.5f) * rsq_neglog2(y0);
    float wvB = __builtin_amdgcn_exp2f((xpB - mB) * 0.5f) * rsq_neglog2(y1);
    float swA = wvA, swB = wvB;
    #pragma unroll
    for (int off = 1; off < 8; off <<= 1) {
      s0A += __shfl_xor(s0A, off);
      s1A += __shfl_xor(s1A, off);
      s0B += __shfl_xor(s0B, off);
      s1B += __shfl_xor(s1B, off);
      swA += __shfl_xor(swA, off);
      swB += __shfl_xor(swB, off);
    }
    wv_s[u_ * 16 + n] = wvA;
    wv_s[u_ * 16 + 8 + n] = wvB;
    if (n == 0) {
      inv_s[u_ * 2 + 0] = __builtin_amdgcn_rcpf(swA);
      inv_s[u_ * 2 + 1] = __builtin_amdgcn_rcpf(swB);
      atomicAdd(&kl_s,
          LN2 * ((s1A * __builtin_amdgcn_rcpf(s0A) - mA) - __builtin_amdgcn_logf(s0A)) +
          LN2 * ((s1B * __builtin_amdgcn_rcpf(s0B) - mB) - __builtin_amdgcn_logf(s0B)) +
          4.1588830833596715f);
    }
  }
  __syncthreads();

  // ---- 5b phase B: thread = (row r, dim e); q = sum_n wv*emb / sum ----
  float* q_s = x_s;   // x dead (frags extracted pre-loop)
  {
    const int r = t >> 4, e = t & 15;      // r 0..31
    const int p = r & 15, h = r >> 4;
    #pragma unroll
    for (int k = 0; k < 4; ++k) {
      const int u_ = p * 4 + k;
      float aa = 0.f;
      #pragma unroll
      for (int n = 0; n < 8; ++n)
        aa += wv_s[u_ * 16 + h * 8 + n] * emb_s[(k * 8 + n) * 16 + e];
      q_s[r * X_STRIDE + k * 16 + e] = aa * inv_s[u_ * 2 + h];
    }
  }
  __syncthreads();

  // ---- copyout quantized (coalesced) + loss; last block finalizes loss ----
  #pragma unroll
  for (int it = 0; it < 4; ++it) {
    int idx = it * 512 + t;
    int rl = idx >> 6, c = idx & 63;
    int row = (rl < 16) ? (g0 + rl) : (g0 + rl - 16 + NROWS_HALF);
    out[row * 64 + c] = q_s[rl * X_STRIDE + c];
  }
  if (t == 0) {
    atomicAdd(loss_acc, kl_s);
    __threadfence();
    uint32_t tk = atomicAdd(&g_ticket, 1u);
    if (tk == 2047u) {
      __threadfence();
      out[LOSS_OFF] = atomicAdd(loss_acc, 0.0f) * 0.2f;
    }
  }
}

extern "C" void kernel_launch(void* const* d_in, const int* in_sizes, int n_in,
                              void* d_out, int out_size, void* d_ws, size_t ws_size,
                              hipStream_t stream) {
  const float* inp  = (const float*)d_in[0];   // [32,2048,64]
  const float* lw   = (const float*)d_in[1];   // [64,3]
  const float* lb   = (const float*)d_in[2];   // [64]
  const float* emb  = (const float*)d_in[3];   // [32,16] normalized
  const float* lws  = (const float*)d_in[4];   // [4,16,64]
  float* out = (float*)d_out;
  ushort* wsu = (ushort*)d_ws;
  float* loss = (float*)((char*)d_ws + WS_LOSS_BYTE);

  // JAX PRNG keys: key(42) -> [0,42]; split = threefry over iota(4)
  uint32_t a0, b0, a1, b1;
  tf2x32(0u, 42u, 0u, 2u, a0, b0);
  tf2x32(0u, 42u, 1u, 3u, a1, b1);
  const uint32_t kc0 = a0, kc1 = a1;   // coord-noise key
  const uint32_t kp0 = b0, kp1 = b1;   // codebook-noise key

  setup_kernel<<<9, 256, 0, stream>>>(emb, lws, wsu);
  fused_kernel<<<2048, 512, 0, stream>>>(inp, emb, lw, lb, wsu, out, loss,
                                         kc0, kc1, kp0, kp1);
}